// Round 1
// baseline (793.828 us; speedup 1.0000x reference)
//
#include <hip/hip_runtime.h>
#include <hip/hip_bf16.h>
#include <cstdint>

#define T_TOK 8192
#define DDIM 1024
#define FDIM 4096
#define NEXP 8

typedef short short8 __attribute__((ext_vector_type(8)));
typedef float floatx4 __attribute__((ext_vector_type(4)));

// round-to-nearest-even f32 -> bf16
__device__ __forceinline__ short f2bf(float f) {
  unsigned u = __float_as_uint(f);
  unsigned r = (u + 0x7fffu + ((u >> 16) & 1u)) >> 16;
  return (short)r;
}

// async global -> LDS, 16B per lane (dest = wave-uniform base + lane*16)
__device__ __forceinline__ void load_lds16(const void* g, void* l) {
  __builtin_amdgcn_global_load_lds(
      (__attribute__((address_space(1))) unsigned int*)g,
      (__attribute__((address_space(3))) unsigned int*)l, 16, 0, 0);
}

// ---------------- router: one wave per token ----------------
__global__ __launch_bounds__(256) void router_kernel(
    const float* __restrict__ x, const float* __restrict__ rw,
    const float* __restrict__ rb, int* __restrict__ expert_t,
    int* __restrict__ pos_t, float* __restrict__ gate_t,
    int* __restrict__ counts, float* __restrict__ probsum) {
  __shared__ float w[NEXP * DDIM];  // 32 KiB
  int tid = threadIdx.x;
  for (int i = tid; i < NEXP * DDIM; i += 256) w[i] = rw[i];
  __syncthreads();
  int wid = tid >> 6, lane = tid & 63;
  int t = blockIdx.x * 4 + wid;
  const float* xr = x + (size_t)t * DDIM;
  float acc[NEXP];
#pragma unroll
  for (int e = 0; e < NEXP; e++) acc[e] = 0.f;
  for (int kk = 0; kk < DDIM / 64; kk++) {
    float xv = xr[lane + 64 * kk];
#pragma unroll
    for (int e = 0; e < NEXP; e++) acc[e] += xv * w[e * DDIM + lane + 64 * kk];
  }
#pragma unroll
  for (int e = 0; e < NEXP; e++) {
#pragma unroll
    for (int off = 32; off > 0; off >>= 1) acc[e] += __shfl_xor(acc[e], off);
  }
  if (lane == 0) {
    float l[NEXP];
#pragma unroll
    for (int e = 0; e < NEXP; e++) l[e] = acc[e] + rb[e];
    int best = 0;
    float lm = l[0];
#pragma unroll
    for (int e = 1; e < NEXP; e++)
      if (l[e] > lm) { lm = l[e]; best = e; }
    float s = 0.f;
#pragma unroll
    for (int e = 0; e < NEXP; e++) s += expf(l[e] - lm);
    float gate = 1.f / s;  // softmax prob of argmax
    expert_t[t] = best;
    gate_t[t] = gate;
    pos_t[t] = atomicAdd(&counts[best], 1);
    atomicAdd(&probsum[best], gate);
  }
}

// ---------------- finalize: offsets scan + aux loss ----------------
__global__ void finalize_kernel(const int* __restrict__ counts,
                                const float* __restrict__ probsum,
                                int* __restrict__ offsets,
                                float* __restrict__ loss_out) {
  if (threadIdx.x == 0 && blockIdx.x == 0) {
    int off = 0;
    float loss = 0.f;
    for (int e = 0; e < NEXP; e++) {
      offsets[e] = off;
      off += counts[e];
      loss += ((float)counts[e] / (float)T_TOK) *
              (probsum[e] / ((float)T_TOK * (float)T_TOK));
    }
    offsets[NEXP] = off;
    *loss_out = loss * 3e-6f * (float)NEXP;
  }
}

// ---------------- gather x rows into expert-sorted bf16 A ----------------
__global__ __launch_bounds__(256) void gather_kernel(
    const float* __restrict__ x, const int* __restrict__ expert_t,
    const int* __restrict__ pos_t, const float* __restrict__ gate_t,
    const int* __restrict__ offsets, short* __restrict__ Abuf,
    int* __restrict__ tok_of_row, float* __restrict__ gate_row) {
  int tid = threadIdx.x;
  int wid = tid >> 6, lane = tid & 63;
  int t = blockIdx.x * 4 + wid;
  int row = offsets[expert_t[t]] + pos_t[t];
  if (lane == 0) {
    tok_of_row[row] = t;
    gate_row[row] = gate_t[t];
  }
  const float4* xs = (const float4*)(x + (size_t)t * DDIM);
  uint2* ad = (uint2*)(Abuf + (size_t)row * DDIM);
#pragma unroll
  for (int i = 0; i < 4; i++) {
    float4 v = xs[lane + 64 * i];
    uint2 p;
    p.x = (unsigned)(unsigned short)f2bf(v.x) |
          ((unsigned)(unsigned short)f2bf(v.y) << 16);
    p.y = (unsigned)(unsigned short)f2bf(v.z) |
          ((unsigned)(unsigned short)f2bf(v.w) << 16);
    ad[lane + 64 * i] = p;
  }
}

// ---------------- transpose+convert weights: [E][R][C] f32 -> [E][C][R] bf16
__global__ __launch_bounds__(256) void transpose_bf16_kernel(
    const float* __restrict__ src, short* __restrict__ dst, int R, int C) {
  __shared__ float tile[64][65];
  long long base = (long long)blockIdx.z * R * C;
  const float* s = src + base;
  short* d = dst + base;
  int r0 = blockIdx.y * 64, c0 = blockIdx.x * 64;
  int tid = threadIdx.x;
  for (int i = tid; i < 64 * 64; i += 256) {
    int r = i >> 6, c = i & 63;
    tile[r][c] = s[(size_t)(r0 + r) * C + c0 + c];
  }
  __syncthreads();
  for (int i = tid; i < 64 * 32; i += 256) {
    int cc = i >> 5, rr = (i & 31) * 2;
    unsigned lo = (unsigned short)f2bf(tile[rr][cc]);
    unsigned hi = (unsigned short)f2bf(tile[rr + 1][cc]);
    *(unsigned*)(d + (size_t)(c0 + cc) * R + r0 + rr) = lo | (hi << 16);
  }
}

// ---------------- m97-style bf16 GEMM, 128x128 tile, BK=64 ----------------
// A: [T, KDIM] bf16 expert-sorted rows. Bw: [E][NDIM][KDIM] bf16 (k-contig).
// FFN1: Hout[row, n] = bf16(relu(acc)). FFN2: Out[tok, n] = acc * gate.
template <int KDIM, int NDIM, bool FFN1>
__global__ __launch_bounds__(256) void gemm_kernel(
    const short* __restrict__ A, const short* __restrict__ Bw,
    short* __restrict__ Hout, float* __restrict__ Out,
    const int* __restrict__ counts, const int* __restrict__ offsets,
    const int* __restrict__ tok_of_row, const float* __restrict__ gate_row) {
  int e = blockIdx.z;
  int Me = counts[e];
  int m0 = blockIdx.y * 128;
  if (m0 >= Me) return;
  int rowBase = offsets[e];
  int n0 = blockIdx.x * 128;

  __shared__ short As[128 * 64];  // [m][k], rows of 128 B
  __shared__ short Bs[128 * 64];  // [n][k]

  int tid = threadIdx.x;
  int wid = tid >> 6, lane = tid & 63;
  int wm = wid >> 1, wn = wid & 1;

  // staging pointers: chunk ci = (wid*4+it)*64 + lane; row = ci>>3, 16B col = ci&7
  const short* aP[4];
  const short* bP[4];
#pragma unroll
  for (int it = 0; it < 4; it++) {
    int ci = (wid * 4 + it) * 64 + lane;
    int r = ci >> 3, c = ci & 7;
    int ar = m0 + r;
    if (ar > Me - 1) ar = Me - 1;  // clamp pad rows to a valid row
    aP[it] = A + (size_t)(rowBase + ar) * KDIM + c * 8;
    bP[it] = Bw + ((size_t)e * NDIM + (n0 + r)) * (size_t)KDIM + c * 8;
  }

  floatx4 acc[4][4];
#pragma unroll
  for (int i = 0; i < 4; i++)
#pragma unroll
    for (int j = 0; j < 4; j++) acc[i][j] = floatx4{0.f, 0.f, 0.f, 0.f};

  for (int k0 = 0; k0 < KDIM; k0 += 64) {
#pragma unroll
    for (int it = 0; it < 4; it++) {
      load_lds16(aP[it], (char*)As + (wid * 4 + it) * 1024);
      load_lds16(bP[it], (char*)Bs + (wid * 4 + it) * 1024);
      aP[it] += 64;
      bP[it] += 64;
    }
    __syncthreads();  // compiler drains vmcnt before s_barrier
#pragma unroll
    for (int ks = 0; ks < 64; ks += 32) {
      int kk = ks + (lane >> 4) * 8;
      short8 af[4], bfv[4];
#pragma unroll
      for (int i = 0; i < 4; i++) {
        int m = wm * 64 + i * 16 + (lane & 15);
        af[i] = *(const short8*)&As[m * 64 + kk];
        int n = wn * 64 + i * 16 + (lane & 15);
        bfv[i] = *(const short8*)&Bs[n * 64 + kk];
      }
#pragma unroll
      for (int i = 0; i < 4; i++)
#pragma unroll
        for (int j = 0; j < 4; j++)
          acc[i][j] = __builtin_amdgcn_mfma_f32_16x16x32_bf16(af[i], bfv[j],
                                                              acc[i][j], 0, 0, 0);
    }
    __syncthreads();
  }

  // epilogue. C/D layout: col = lane&15, row = (lane>>4)*4 + reg  [m89]
  int colBase = n0 + wn * 64 + (lane & 15);
#pragma unroll
  for (int i = 0; i < 4; i++) {
    int mBase = m0 + wm * 64 + i * 16 + ((lane >> 4) << 2);
#pragma unroll
    for (int r = 0; r < 4; r++) {
      int m = mBase + r;
      if (m < Me) {
        int grow = rowBase + m;
        if constexpr (FFN1) {
#pragma unroll
          for (int j = 0; j < 4; j++) {
            float v = acc[i][j][r];
            v = v > 0.f ? v : 0.f;
            Hout[(size_t)grow * NDIM + colBase + j * 16] = f2bf(v);
          }
        } else {
          int t = tok_of_row[grow];
          float g = gate_row[grow];
#pragma unroll
          for (int j = 0; j < 4; j++)
            Out[(size_t)t * NDIM + colBase + j * 16] = acc[i][j][r] * g;
        }
      }
    }
  }
}

extern "C" void kernel_launch(void* const* d_in, const int* in_sizes, int n_in,
                              void* d_out, int out_size, void* d_ws,
                              size_t ws_size, hipStream_t stream) {
  const float* x = (const float*)d_in[0];
  const float* w1 = (const float*)d_in[1];
  const float* w2 = (const float*)d_in[2];
  const float* rw = (const float*)d_in[3];
  const float* rb = (const float*)d_in[4];
  float* out = (float*)d_out;
  float* loss_out = out + (out_size - 1);  // loss scalar at tail

  char* ws = (char*)d_ws;
  size_t o = 0;
  auto alloc = [&](size_t bytes) {
    char* p = ws + o;
    o += (bytes + 255) & ~(size_t)255;
    return p;
  };
  short* W1T = (short*)alloc((size_t)NEXP * FDIM * DDIM * 2);  // [E][F][D] bf16
  short* W2T = (short*)alloc((size_t)NEXP * DDIM * FDIM * 2);  // [E][D][F] bf16
  short* Abuf = (short*)alloc((size_t)T_TOK * DDIM * 2);       // sorted x bf16
  short* Hbuf = (short*)alloc((size_t)T_TOK * FDIM * 2);       // relu(h) bf16
  int* tok_of_row = (int*)alloc(T_TOK * 4);
  float* gate_row = (float*)alloc(T_TOK * 4);
  int* expert_t = (int*)alloc(T_TOK * 4);
  int* pos_t = (int*)alloc(T_TOK * 4);
  float* gate_t = (float*)alloc(T_TOK * 4);
  int* counts = (int*)alloc(64);
  float* probsum = (float*)alloc(64);
  int* offsets = (int*)alloc(64);

  hipMemsetAsync(counts, 0, 64, stream);
  hipMemsetAsync(probsum, 0, 64, stream);

  // weight convert+transpose: w1 [E][1024][4096] -> W1T [E][4096][1024]
  transpose_bf16_kernel<<<dim3(64, 16, NEXP), 256, 0, stream>>>(w1, W1T, DDIM, FDIM);
  // w2 [E][4096][1024] -> W2T [E][1024][4096]
  transpose_bf16_kernel<<<dim3(16, 64, NEXP), 256, 0, stream>>>(w2, W2T, FDIM, DDIM);

  router_kernel<<<T_TOK / 4, 256, 0, stream>>>(x, rw, rb, expert_t, pos_t,
                                               gate_t, counts, probsum);
  finalize_kernel<<<1, 64, 0, stream>>>(counts, probsum, offsets, loss_out);
  gather_kernel<<<T_TOK / 4, 256, 0, stream>>>(x, expert_t, pos_t, gate_t,
                                               offsets, Abuf, tok_of_row, gate_row);

  // FFN1: [n_e,1024] @ [1024,4096] -> relu -> Hbuf bf16
  gemm_kernel<DDIM, FDIM, true><<<dim3(FDIM / 128, T_TOK / 128, NEXP), 256, 0,
                                  stream>>>(Abuf, W1T, Hbuf, nullptr, counts,
                                            offsets, nullptr, nullptr);
  // FFN2: [n_e,4096] @ [4096,1024] -> *gate -> scatter to out fp32
  gemm_kernel<FDIM, DDIM, false><<<dim3(DDIM / 128, T_TOK / 128, NEXP), 256, 0,
                                   stream>>>(Hbuf, W2T, nullptr, out, counts,
                                             offsets, tok_of_row, gate_row);
}

// Round 2
// 791.952 us; speedup vs baseline: 1.0024x; 1.0024x over previous
//
#include <hip/hip_runtime.h>
#include <hip/hip_bf16.h>
#include <cstdint>

#define T_TOK 8192
#define DDIM 1024
#define FDIM 4096
#define NEXP 8
#define MAX_TILES 72

typedef short short8 __attribute__((ext_vector_type(8)));
typedef float floatx4 __attribute__((ext_vector_type(4)));

// round-to-nearest-even f32 -> bf16
__device__ __forceinline__ short f2bf(float f) {
  unsigned u = __float_as_uint(f);
  unsigned r = (u + 0x7fffu + ((u >> 16) & 1u)) >> 16;
  return (short)r;
}

// async global -> LDS, 16B per lane (dest = wave-uniform base + lane*16)
__device__ __forceinline__ void load_lds16(const void* g, void* l) {
  __builtin_amdgcn_global_load_lds(
      (__attribute__((address_space(1))) unsigned int*)g,
      (__attribute__((address_space(3))) unsigned int*)l, 16, 0, 0);
}

// ---------------- router: one wave per token ----------------
__global__ __launch_bounds__(256) void router_kernel(
    const float* __restrict__ x, const float* __restrict__ rw,
    const float* __restrict__ rb, int* __restrict__ expert_t,
    int* __restrict__ pos_t, float* __restrict__ gate_t,
    int* __restrict__ counts, float* __restrict__ probsum) {
  __shared__ float w[NEXP * DDIM];  // 32 KiB
  int tid = threadIdx.x;
  for (int i = tid; i < NEXP * DDIM; i += 256) w[i] = rw[i];
  __syncthreads();
  int wid = tid >> 6, lane = tid & 63;
  int t = blockIdx.x * 4 + wid;
  const float* xr = x + (size_t)t * DDIM;
  float acc[NEXP];
#pragma unroll
  for (int e = 0; e < NEXP; e++) acc[e] = 0.f;
  for (int kk = 0; kk < DDIM / 64; kk++) {
    float xv = xr[lane + 64 * kk];
#pragma unroll
    for (int e = 0; e < NEXP; e++) acc[e] += xv * w[e * DDIM + lane + 64 * kk];
  }
#pragma unroll
  for (int e = 0; e < NEXP; e++) {
#pragma unroll
    for (int off = 32; off > 0; off >>= 1) acc[e] += __shfl_xor(acc[e], off);
  }
  if (lane == 0) {
    float l[NEXP];
#pragma unroll
    for (int e = 0; e < NEXP; e++) l[e] = acc[e] + rb[e];
    int best = 0;
    float lm = l[0];
#pragma unroll
    for (int e = 1; e < NEXP; e++)
      if (l[e] > lm) { lm = l[e]; best = e; }
    float s = 0.f;
#pragma unroll
    for (int e = 0; e < NEXP; e++) s += expf(l[e] - lm);
    float gate = 1.f / s;  // softmax prob of argmax
    expert_t[t] = best;
    gate_t[t] = gate;
    pos_t[t] = atomicAdd(&counts[best], 1);
    atomicAdd(&probsum[best], gate);
  }
}

// ------- finalize: offsets scan + aux loss + compact (expert, m0) tile list
__global__ void finalize_kernel(const int* __restrict__ counts,
                                const float* __restrict__ probsum,
                                int* __restrict__ offsets,
                                float* __restrict__ loss_out,
                                int* __restrict__ tileE,
                                int* __restrict__ tileM,
                                int* __restrict__ ntiles) {
  if (threadIdx.x == 0 && blockIdx.x == 0) {
    int off = 0;
    float loss = 0.f;
    int nt = 0;
    for (int e = 0; e < NEXP; e++) {
      offsets[e] = off;
      off += counts[e];
      loss += ((float)counts[e] / (float)T_TOK) *
              (probsum[e] / ((float)T_TOK * (float)T_TOK));
      for (int m = 0; m < counts[e]; m += 128) {
        tileE[nt] = e;
        tileM[nt] = m;
        nt++;
      }
    }
    offsets[NEXP] = off;
    *ntiles = nt;
    *loss_out = loss * 3e-6f * (float)NEXP;
  }
}

// ---------------- gather x rows into expert-sorted bf16 A ----------------
__global__ __launch_bounds__(256) void gather_kernel(
    const float* __restrict__ x, const int* __restrict__ expert_t,
    const int* __restrict__ pos_t, const float* __restrict__ gate_t,
    const int* __restrict__ offsets, short* __restrict__ Abuf,
    int* __restrict__ tok_of_row, float* __restrict__ gate_row) {
  int tid = threadIdx.x;
  int wid = tid >> 6, lane = tid & 63;
  int t = blockIdx.x * 4 + wid;
  int row = offsets[expert_t[t]] + pos_t[t];
  if (lane == 0) {
    tok_of_row[row] = t;
    gate_row[row] = gate_t[t];
  }
  const float4* xs = (const float4*)(x + (size_t)t * DDIM);
  uint2* ad = (uint2*)(Abuf + (size_t)row * DDIM);
#pragma unroll
  for (int i = 0; i < 4; i++) {
    float4 v = xs[lane + 64 * i];
    uint2 p;
    p.x = (unsigned)(unsigned short)f2bf(v.x) |
          ((unsigned)(unsigned short)f2bf(v.y) << 16);
    p.y = (unsigned)(unsigned short)f2bf(v.z) |
          ((unsigned)(unsigned short)f2bf(v.w) << 16);
    ad[lane + 64 * i] = p;
  }
}

// ---------------- transpose+convert weights: [E][R][C] f32 -> [E][C][R] bf16
__global__ __launch_bounds__(256) void transpose_bf16_kernel(
    const float* __restrict__ src, short* __restrict__ dst, int R, int C) {
  __shared__ float tile[64][65];
  long long base = (long long)blockIdx.z * R * C;
  const float* s = src + base;
  short* d = dst + base;
  int r0 = blockIdx.y * 64, c0 = blockIdx.x * 64;
  int tid = threadIdx.x;
  for (int i = tid; i < 64 * 64; i += 256) {
    int r = i >> 6, c = i & 63;
    tile[r][c] = s[(size_t)(r0 + r) * C + c0 + c];
  }
  __syncthreads();
  for (int i = tid; i < 64 * 32; i += 256) {
    int cc = i >> 5, rr = (i & 31) * 2;
    unsigned lo = (unsigned short)f2bf(tile[rr][cc]);
    unsigned hi = (unsigned short)f2bf(tile[rr + 1][cc]);
    *(unsigned*)(d + (size_t)(c0 + cc) * R + r0 + rr) = lo | (hi << 16);
  }
}

// ---------------- m97-style bf16 GEMM, 128x128 tile, BK=64 ----------------
// A: [T, KDIM] bf16 expert-sorted rows. Bw: [E][NDIM][KDIM] bf16 (k-contig).
// Work tiles come from the compact (tileE, tileM) list -> dense dispatch.
// FFN1: Hout[row, n] = bf16(relu(acc)). FFN2: Out[tok, n] = acc * gate.
template <int KDIM, int NDIM, bool FFN1>
__global__ __launch_bounds__(256) void gemm_kernel(
    const short* __restrict__ A, const short* __restrict__ Bw,
    short* __restrict__ Hout, float* __restrict__ Out,
    const int* __restrict__ counts, const int* __restrict__ offsets,
    const int* __restrict__ tok_of_row, const float* __restrict__ gate_row,
    const int* __restrict__ tileE, const int* __restrict__ tileM,
    const int* __restrict__ ntiles) {
  int ti = blockIdx.y;
  if (ti >= *ntiles) return;
  int e = tileE[ti];
  int m0 = tileM[ti];
  int Me = counts[e];
  int rowBase = offsets[e];
  int n0 = blockIdx.x * 128;

  __shared__ short As[128 * 64];  // [m][k], rows of 128 B
  __shared__ short Bs[128 * 64];  // [n][k]

  int tid = threadIdx.x;
  int wid = tid >> 6, lane = tid & 63;
  int wm = wid >> 1, wn = wid & 1;

  // staging pointers: chunk ci = (wid*4+it)*64 + lane; row = ci>>3, 16B col = ci&7
  const short* aP[4];
  const short* bP[4];
#pragma unroll
  for (int it = 0; it < 4; it++) {
    int ci = (wid * 4 + it) * 64 + lane;
    int r = ci >> 3, c = ci & 7;
    int ar = m0 + r;
    if (ar > Me - 1) ar = Me - 1;  // clamp pad rows to a valid row
    aP[it] = A + (size_t)(rowBase + ar) * KDIM + c * 8;
    bP[it] = Bw + ((size_t)e * NDIM + (n0 + r)) * (size_t)KDIM + c * 8;
  }

  floatx4 acc[4][4];
#pragma unroll
  for (int i = 0; i < 4; i++)
#pragma unroll
    for (int j = 0; j < 4; j++) acc[i][j] = floatx4{0.f, 0.f, 0.f, 0.f};

  for (int k0 = 0; k0 < KDIM; k0 += 64) {
#pragma unroll
    for (int it = 0; it < 4; it++) {
      load_lds16(aP[it], (char*)As + (wid * 4 + it) * 1024);
      load_lds16(bP[it], (char*)Bs + (wid * 4 + it) * 1024);
      aP[it] += 64;
      bP[it] += 64;
    }
    __syncthreads();  // compiler drains vmcnt before s_barrier
#pragma unroll
    for (int ks = 0; ks < 64; ks += 32) {
      int kk = ks + (lane >> 4) * 8;
      short8 af[4], bfv[4];
#pragma unroll
      for (int i = 0; i < 4; i++) {
        int m = wm * 64 + i * 16 + (lane & 15);
        af[i] = *(const short8*)&As[m * 64 + kk];
        int n = wn * 64 + i * 16 + (lane & 15);
        bfv[i] = *(const short8*)&Bs[n * 64 + kk];
      }
#pragma unroll
      for (int i = 0; i < 4; i++)
#pragma unroll
        for (int j = 0; j < 4; j++)
          acc[i][j] = __builtin_amdgcn_mfma_f32_16x16x32_bf16(af[i], bfv[j],
                                                              acc[i][j], 0, 0, 0);
    }
    __syncthreads();
  }

  // epilogue. C/D layout: col = lane&15, row = (lane>>4)*4 + reg  [m89]
  int colBase = n0 + wn * 64 + (lane & 15);
#pragma unroll
  for (int i = 0; i < 4; i++) {
    int mBase = m0 + wm * 64 + i * 16 + ((lane >> 4) << 2);
#pragma unroll
    for (int r = 0; r < 4; r++) {
      int m = mBase + r;
      if (m < Me) {
        int grow = rowBase + m;
        if constexpr (FFN1) {
#pragma unroll
          for (int j = 0; j < 4; j++) {
            float v = acc[i][j][r];
            v = v > 0.f ? v : 0.f;
            Hout[(size_t)grow * NDIM + colBase + j * 16] = f2bf(v);
          }
        } else {
          int t = tok_of_row[grow];
          float g = gate_row[grow];
#pragma unroll
          for (int j = 0; j < 4; j++)
            Out[(size_t)t * NDIM + colBase + j * 16] = acc[i][j][r] * g;
        }
      }
    }
  }
}

extern "C" void kernel_launch(void* const* d_in, const int* in_sizes, int n_in,
                              void* d_out, int out_size, void* d_ws,
                              size_t ws_size, hipStream_t stream) {
  const float* x = (const float*)d_in[0];
  const float* w1 = (const float*)d_in[1];
  const float* w2 = (const float*)d_in[2];
  const float* rw = (const float*)d_in[3];
  const float* rb = (const float*)d_in[4];
  float* out = (float*)d_out;
  float* loss_out = out + (out_size - 1);  // loss scalar at tail

  char* ws = (char*)d_ws;
  size_t o = 0;
  auto alloc = [&](size_t bytes) {
    char* p = ws + o;
    o += (bytes + 255) & ~(size_t)255;
    return p;
  };
  short* W1T = (short*)alloc((size_t)NEXP * FDIM * DDIM * 2);  // [E][F][D] bf16
  short* W2T = (short*)alloc((size_t)NEXP * DDIM * FDIM * 2);  // [E][D][F] bf16
  short* Abuf = (short*)alloc((size_t)T_TOK * DDIM * 2);       // sorted x bf16
  short* Hbuf = (short*)alloc((size_t)T_TOK * FDIM * 2);       // relu(h) bf16
  int* tok_of_row = (int*)alloc(T_TOK * 4);
  float* gate_row = (float*)alloc(T_TOK * 4);
  int* expert_t = (int*)alloc(T_TOK * 4);
  int* pos_t = (int*)alloc(T_TOK * 4);
  float* gate_t = (float*)alloc(T_TOK * 4);
  int* counts = (int*)alloc(64);
  float* probsum = (float*)alloc(64);
  int* offsets = (int*)alloc(64);
  int* tileE = (int*)alloc(MAX_TILES * 4);
  int* tileM = (int*)alloc(MAX_TILES * 4);
  int* ntiles = (int*)alloc(64);

  hipMemsetAsync(counts, 0, 64, stream);
  hipMemsetAsync(probsum, 0, 64, stream);

  // weight convert+transpose: w1 [E][1024][4096] -> W1T [E][4096][1024]
  transpose_bf16_kernel<<<dim3(64, 16, NEXP), 256, 0, stream>>>(w1, W1T, DDIM, FDIM);
  // w2 [E][4096][1024] -> W2T [E][1024][4096]
  transpose_bf16_kernel<<<dim3(16, 64, NEXP), 256, 0, stream>>>(w2, W2T, FDIM, DDIM);

  router_kernel<<<T_TOK / 4, 256, 0, stream>>>(x, rw, rb, expert_t, pos_t,
                                               gate_t, counts, probsum);
  finalize_kernel<<<1, 64, 0, stream>>>(counts, probsum, offsets, loss_out,
                                        tileE, tileM, ntiles);
  gather_kernel<<<T_TOK / 4, 256, 0, stream>>>(x, expert_t, pos_t, gate_t,
                                               offsets, Abuf, tok_of_row, gate_row);

  // FFN1: [n_e,1024] @ [1024,4096] -> relu -> Hbuf bf16
  gemm_kernel<DDIM, FDIM, true><<<dim3(FDIM / 128, MAX_TILES), 256, 0, stream>>>(
      Abuf, W1T, Hbuf, nullptr, counts, offsets, nullptr, nullptr, tileE, tileM,
      ntiles);
  // FFN2: [n_e,4096] @ [4096,1024] -> *gate -> scatter to out fp32
  gemm_kernel<FDIM, DDIM, false><<<dim3(DDIM / 128, MAX_TILES), 256, 0, stream>>>(
      Hbuf, W2T, nullptr, out, counts, offsets, tok_of_row, gate_row, tileE,
      tileM, ntiles);
}

// Round 3
// 736.081 us; speedup vs baseline: 1.0785x; 1.0759x over previous
//
#include <hip/hip_runtime.h>
#include <hip/hip_bf16.h>
#include <cstdint>

#define T_TOK 8192
#define DDIM 1024
#define FDIM 4096
#define NEXP 8
#define MAX_TILES 72

typedef short short8 __attribute__((ext_vector_type(8)));
typedef float floatx4 __attribute__((ext_vector_type(4)));

// round-to-nearest-even f32 -> bf16
__device__ __forceinline__ short f2bf(float f) {
  unsigned u = __float_as_uint(f);
  unsigned r = (u + 0x7fffu + ((u >> 16) & 1u)) >> 16;
  return (short)r;
}

// async global -> LDS, 16B per lane (dest = wave-uniform base + lane*16)
__device__ __forceinline__ void load_lds16(const void* g, void* l) {
  __builtin_amdgcn_global_load_lds(
      (__attribute__((address_space(1))) unsigned int*)g,
      (__attribute__((address_space(3))) unsigned int*)l, 16, 0, 0);
}

// ---------------- router: one wave per token ----------------
__global__ __launch_bounds__(256) void router_kernel(
    const float* __restrict__ x, const float* __restrict__ rw,
    const float* __restrict__ rb, int* __restrict__ expert_t,
    int* __restrict__ pos_t, float* __restrict__ gate_t,
    int* __restrict__ counts, float* __restrict__ probsum) {
  __shared__ float w[NEXP * DDIM];  // 32 KiB
  int tid = threadIdx.x;
  for (int i = tid; i < NEXP * DDIM; i += 256) w[i] = rw[i];
  __syncthreads();
  int wid = tid >> 6, lane = tid & 63;
  int t = blockIdx.x * 4 + wid;
  const float* xr = x + (size_t)t * DDIM;
  float acc[NEXP];
#pragma unroll
  for (int e = 0; e < NEXP; e++) acc[e] = 0.f;
  for (int kk = 0; kk < DDIM / 64; kk++) {
    float xv = xr[lane + 64 * kk];
#pragma unroll
    for (int e = 0; e < NEXP; e++) acc[e] += xv * w[e * DDIM + lane + 64 * kk];
  }
#pragma unroll
  for (int e = 0; e < NEXP; e++) {
#pragma unroll
    for (int off = 32; off > 0; off >>= 1) acc[e] += __shfl_xor(acc[e], off);
  }
  if (lane == 0) {
    float l[NEXP];
#pragma unroll
    for (int e = 0; e < NEXP; e++) l[e] = acc[e] + rb[e];
    int best = 0;
    float lm = l[0];
#pragma unroll
    for (int e = 1; e < NEXP; e++)
      if (l[e] > lm) { lm = l[e]; best = e; }
    float s = 0.f;
#pragma unroll
    for (int e = 0; e < NEXP; e++) s += expf(l[e] - lm);
    float gate = 1.f / s;  // softmax prob of argmax
    expert_t[t] = best;
    gate_t[t] = gate;
    pos_t[t] = atomicAdd(&counts[best], 1);
    atomicAdd(&probsum[best], gate);
  }
}

// ------- finalize: offsets scan + aux loss + compact (expert, m0) tile list
__global__ void finalize_kernel(const int* __restrict__ counts,
                                const float* __restrict__ probsum,
                                int* __restrict__ offsets,
                                float* __restrict__ loss_out,
                                int* __restrict__ tileE,
                                int* __restrict__ tileM,
                                int* __restrict__ ntiles) {
  if (threadIdx.x == 0 && blockIdx.x == 0) {
    int off = 0;
    float loss = 0.f;
    int nt = 0;
    for (int e = 0; e < NEXP; e++) {
      offsets[e] = off;
      off += counts[e];
      loss += ((float)counts[e] / (float)T_TOK) *
              (probsum[e] / ((float)T_TOK * (float)T_TOK));
      for (int m = 0; m < counts[e]; m += 128) {
        tileE[nt] = e;
        tileM[nt] = m;
        nt++;
      }
    }
    offsets[NEXP] = off;
    *ntiles = nt;
    *loss_out = loss * 3e-6f * (float)NEXP;
  }
}

// ---------------- gather x rows into expert-sorted bf16 A ----------------
__global__ __launch_bounds__(256) void gather_kernel(
    const float* __restrict__ x, const int* __restrict__ expert_t,
    const int* __restrict__ pos_t, const float* __restrict__ gate_t,
    const int* __restrict__ offsets, short* __restrict__ Abuf,
    int* __restrict__ tok_of_row, float* __restrict__ gate_row) {
  int tid = threadIdx.x;
  int wid = tid >> 6, lane = tid & 63;
  int t = blockIdx.x * 4 + wid;
  int row = offsets[expert_t[t]] + pos_t[t];
  if (lane == 0) {
    tok_of_row[row] = t;
    gate_row[row] = gate_t[t];
  }
  const float4* xs = (const float4*)(x + (size_t)t * DDIM);
  uint2* ad = (uint2*)(Abuf + (size_t)row * DDIM);
#pragma unroll
  for (int i = 0; i < 4; i++) {
    float4 v = xs[lane + 64 * i];
    uint2 p;
    p.x = (unsigned)(unsigned short)f2bf(v.x) |
          ((unsigned)(unsigned short)f2bf(v.y) << 16);
    p.y = (unsigned)(unsigned short)f2bf(v.z) |
          ((unsigned)(unsigned short)f2bf(v.w) << 16);
    ad[lane + 64 * i] = p;
  }
}

// ---------------- transpose+convert weights: [E][R][C] f32 -> [E][C][R] bf16
__global__ __launch_bounds__(256) void transpose_bf16_kernel(
    const float* __restrict__ src, short* __restrict__ dst, int R, int C) {
  __shared__ float tile[64][65];
  long long base = (long long)blockIdx.z * R * C;
  const float* s = src + base;
  short* d = dst + base;
  int r0 = blockIdx.y * 64, c0 = blockIdx.x * 64;
  int tid = threadIdx.x;
  for (int i = tid; i < 64 * 64; i += 256) {
    int r = i >> 6, c = i & 63;
    tile[r][c] = s[(size_t)(r0 + r) * C + c0 + c];
  }
  __syncthreads();
  for (int i = tid; i < 64 * 32; i += 256) {
    int cc = i >> 5, rr = (i & 31) * 2;
    unsigned lo = (unsigned short)f2bf(tile[rr][cc]);
    unsigned hi = (unsigned short)f2bf(tile[rr + 1][cc]);
    *(unsigned*)(d + (size_t)(c0 + cc) * R + r0 + rr) = lo | (hi << 16);
  }
}

// ---------------- m97-style bf16 GEMM, 128x128 tile, BK=64 ----------------
// LDS layout is XOR-swizzled to kill the 16-way bank conflict:
//   LDS slot (row r, 16B-chunk c) holds global k-chunk (c ^ (r&7)).
// The global_load_lds write side stays linear (lane*16); the swizzle is
// applied to the global source pointer (stage) and the read offset (frag).
// A: [T, KDIM] bf16 expert-sorted rows. Bw: [E][NDIM][KDIM] bf16 (k-contig).
// FFN1: Hout[row, n] = bf16(relu(acc)). FFN2: Out[tok, n] = acc * gate.
template <int KDIM, int NDIM, bool FFN1>
__global__ __launch_bounds__(256) void gemm_kernel(
    const short* __restrict__ A, const short* __restrict__ Bw,
    short* __restrict__ Hout, float* __restrict__ Out,
    const int* __restrict__ counts, const int* __restrict__ offsets,
    const int* __restrict__ tok_of_row, const float* __restrict__ gate_row,
    const int* __restrict__ tileE, const int* __restrict__ tileM,
    const int* __restrict__ ntiles) {
  int ti = blockIdx.y;
  if (ti >= *ntiles) return;
  int e = tileE[ti];
  int m0 = tileM[ti];
  int Me = counts[e];
  int rowBase = offsets[e];
  int n0 = blockIdx.x * 128;

  __shared__ short As[128 * 64];  // swizzled [m][k]
  __shared__ short Bs[128 * 64];  // swizzled [n][k]

  int tid = threadIdx.x;
  int wid = tid >> 6, lane = tid & 63;
  int wm = wid >> 1, wn = wid & 1;

  // staging: chunk ci = (wid*4+it)*64 + lane; row r = ci>>3, 16B col c = ci&7.
  // fetch global chunk (c ^ (r&7)) so LDS slot c holds it.
  const short* aP[4];
  const short* bP[4];
#pragma unroll
  for (int it = 0; it < 4; it++) {
    int ci = (wid * 4 + it) * 64 + lane;
    int r = ci >> 3, c = ci & 7;
    int cs = c ^ (r & 7);  // swizzled source chunk
    int ar = m0 + r;
    if (ar > Me - 1) ar = Me - 1;  // clamp pad rows to a valid row
    aP[it] = A + (size_t)(rowBase + ar) * KDIM + cs * 8;
    bP[it] = Bw + ((size_t)e * NDIM + (n0 + r)) * (size_t)KDIM + cs * 8;
  }

  floatx4 acc[4][4];
#pragma unroll
  for (int i = 0; i < 4; i++)
#pragma unroll
    for (int j = 0; j < 4; j++) acc[i][j] = floatx4{0.f, 0.f, 0.f, 0.f};

  int quad = lane >> 4;
  int low3 = lane & 7;  // == m&7 == n&7 for every fragment this lane reads

  for (int k0 = 0; k0 < KDIM; k0 += 64) {
#pragma unroll
    for (int it = 0; it < 4; it++) {
      load_lds16(aP[it], (char*)As + (wid * 4 + it) * 1024);
      load_lds16(bP[it], (char*)Bs + (wid * 4 + it) * 1024);
      aP[it] += 64;
      bP[it] += 64;
    }
    __syncthreads();  // compiler drains vmcnt before s_barrier
#pragma unroll
    for (int ks = 0; ks < 64; ks += 32) {
      int kk16 = (ks >> 3) + quad;          // which 16B k-chunk we need
      int sw = (kk16 ^ low3) * 16;          // swizzled byte offset in row
      short8 af[4], bfv[4];
#pragma unroll
      for (int i = 0; i < 4; i++) {
        int m = wm * 64 + i * 16 + (lane & 15);
        af[i] = *(const short8*)((const char*)As + m * 128 + sw);
        int n = wn * 64 + i * 16 + (lane & 15);
        bfv[i] = *(const short8*)((const char*)Bs + n * 128 + sw);
      }
#pragma unroll
      for (int i = 0; i < 4; i++)
#pragma unroll
        for (int j = 0; j < 4; j++)
          acc[i][j] = __builtin_amdgcn_mfma_f32_16x16x32_bf16(af[i], bfv[j],
                                                              acc[i][j], 0, 0, 0);
    }
    __syncthreads();
  }

  // epilogue. C/D layout: col = lane&15, row = (lane>>4)*4 + reg  [m89]
  int colBase = n0 + wn * 64 + (lane & 15);
#pragma unroll
  for (int i = 0; i < 4; i++) {
    int mBase = m0 + wm * 64 + i * 16 + ((lane >> 4) << 2);
#pragma unroll
    for (int r = 0; r < 4; r++) {
      int m = mBase + r;
      if (m < Me) {
        int grow = rowBase + m;
        if constexpr (FFN1) {
#pragma unroll
          for (int j = 0; j < 4; j++) {
            float v = acc[i][j][r];
            v = v > 0.f ? v : 0.f;
            Hout[(size_t)grow * NDIM + colBase + j * 16] = f2bf(v);
          }
        } else {
          int t = tok_of_row[grow];
          float g = gate_row[grow];
#pragma unroll
          for (int j = 0; j < 4; j++)
            Out[(size_t)t * NDIM + colBase + j * 16] = acc[i][j][r] * g;
        }
      }
    }
  }
}

extern "C" void kernel_launch(void* const* d_in, const int* in_sizes, int n_in,
                              void* d_out, int out_size, void* d_ws,
                              size_t ws_size, hipStream_t stream) {
  const float* x = (const float*)d_in[0];
  const float* w1 = (const float*)d_in[1];
  const float* w2 = (const float*)d_in[2];
  const float* rw = (const float*)d_in[3];
  const float* rb = (const float*)d_in[4];
  float* out = (float*)d_out;
  float* loss_out = out + (out_size - 1);  // loss scalar at tail

  char* ws = (char*)d_ws;
  size_t o = 0;
  auto alloc = [&](size_t bytes) {
    char* p = ws + o;
    o += (bytes + 255) & ~(size_t)255;
    return p;
  };
  short* W1T = (short*)alloc((size_t)NEXP * FDIM * DDIM * 2);  // [E][F][D] bf16
  short* W2T = (short*)alloc((size_t)NEXP * DDIM * FDIM * 2);  // [E][D][F] bf16
  short* Abuf = (short*)alloc((size_t)T_TOK * DDIM * 2);       // sorted x bf16
  short* Hbuf = (short*)alloc((size_t)T_TOK * FDIM * 2);       // relu(h) bf16
  int* tok_of_row = (int*)alloc(T_TOK * 4);
  float* gate_row = (float*)alloc(T_TOK * 4);
  int* expert_t = (int*)alloc(T_TOK * 4);
  int* pos_t = (int*)alloc(T_TOK * 4);
  float* gate_t = (float*)alloc(T_TOK * 4);
  int* counts = (int*)alloc(64);
  float* probsum = (float*)alloc(64);
  int* offsets = (int*)alloc(64);
  int* tileE = (int*)alloc(MAX_TILES * 4);
  int* tileM = (int*)alloc(MAX_TILES * 4);
  int* ntiles = (int*)alloc(64);

  hipMemsetAsync(counts, 0, 64, stream);
  hipMemsetAsync(probsum, 0, 64, stream);

  // weight convert+transpose: w1 [E][1024][4096] -> W1T [E][4096][1024]
  transpose_bf16_kernel<<<dim3(64, 16, NEXP), 256, 0, stream>>>(w1, W1T, DDIM, FDIM);
  // w2 [E][4096][1024] -> W2T [E][1024][4096]
  transpose_bf16_kernel<<<dim3(16, 64, NEXP), 256, 0, stream>>>(w2, W2T, FDIM, DDIM);

  router_kernel<<<T_TOK / 4, 256, 0, stream>>>(x, rw, rb, expert_t, pos_t,
                                               gate_t, counts, probsum);
  finalize_kernel<<<1, 64, 0, stream>>>(counts, probsum, offsets, loss_out,
                                        tileE, tileM, ntiles);
  gather_kernel<<<T_TOK / 4, 256, 0, stream>>>(x, expert_t, pos_t, gate_t,
                                               offsets, Abuf, tok_of_row, gate_row);

  // FFN1: [n_e,1024] @ [1024,4096] -> relu -> Hbuf bf16
  gemm_kernel<DDIM, FDIM, true><<<dim3(FDIM / 128, MAX_TILES), 256, 0, stream>>>(
      Abuf, W1T, Hbuf, nullptr, counts, offsets, nullptr, nullptr, tileE, tileM,
      ntiles);
  // FFN2: [n_e,4096] @ [4096,1024] -> *gate -> scatter to out fp32
  gemm_kernel<FDIM, DDIM, false><<<dim3(DDIM / 128, MAX_TILES), 256, 0, stream>>>(
      Hbuf, W2T, nullptr, out, counts, offsets, tok_of_row, gate_row, tileE,
      tileM, ntiles);
}